// Round 1
// baseline (4157.756 us; speedup 1.0000x reference)
//
#include <hip/hip_runtime.h>

#define N_NODES 262144
#define N_EDGES 2097152
#define EPS_BN 1e-5f

// Monotone float<->uint encoding: preserves order, 0 is a sentinel below -inf.
__device__ __forceinline__ unsigned enc(float f) {
    unsigned u = __float_as_uint(f);
    return (u & 0x80000000u) ? ~u : (u | 0x80000000u);
}
__device__ __forceinline__ float dec(unsigned u) {
    unsigned b = (u & 0x80000000u) ? (u & 0x7FFFFFFFu) : ~u;
    return __uint_as_float(b);
}

// conv1: per-edge message (1+3 -> 16), atomic max-scatter into agg1 (encoded).
__global__ __launch_bounds__(256) void conv1_edges(
    const float* __restrict__ x, const float* __restrict__ pos,
    const int* __restrict__ ei, const float* __restrict__ W1,
    const float* __restrict__ b1, unsigned* __restrict__ agg1)
{
    int e = blockIdx.x * 256 + threadIdx.x;
    if (e >= N_EDGES) return;
    int s = ei[e];
    int d = ei[N_EDGES + e];
    float xs = x[s];
    float rx = pos[3*s+0] - pos[3*d+0];
    float ry = pos[3*s+1] - pos[3*d+1];
    float rz = pos[3*s+2] - pos[3*d+2];
    unsigned* out = agg1 + (size_t)d * 16;
#pragma unroll
    for (int f = 0; f < 16; ++f) {
        float m = b1[f] + xs * W1[f] + rx * W1[16+f] + ry * W1[32+f] + rz * W1[48+f];
        atomicMax(&out[f], enc(m));
    }
}

// node1: decode agg1 (sentinel->0), BN eval + ReLU, write float h1 in-place.
__global__ __launch_bounds__(256) void node1_bn(
    unsigned* __restrict__ agg1,
    const float* __restrict__ mean, const float* __restrict__ var,
    const float* __restrict__ gamma, const float* __restrict__ beta)
{
    int i = blockIdx.x * 256 + threadIdx.x;   // N*16 threads
    int f = i & 15;
    unsigned u = agg1[i];
    float v = (u == 0u) ? 0.0f : dec(u);
    float sc = gamma[f] * rsqrtf(var[f] + EPS_BN);
    float y = (v - mean[f]) * sc + beta[f];
    ((float*)agg1)[i] = fmaxf(y, 0.0f);
}

// conv2: per-edge message (16+3 -> 32), atomic max-scatter into agg2 (encoded).
__global__ __launch_bounds__(256) void conv2_edges(
    const float* __restrict__ h1, const float* __restrict__ pos,
    const int* __restrict__ ei, const float* __restrict__ W2,
    const float* __restrict__ b2, unsigned* __restrict__ agg2)
{
    int e = blockIdx.x * 256 + threadIdx.x;
    if (e >= N_EDGES) return;
    int s = ei[e];
    int d = ei[N_EDGES + e];
    float rx = pos[3*s+0] - pos[3*d+0];
    float ry = pos[3*s+1] - pos[3*d+1];
    float rz = pos[3*s+2] - pos[3*d+2];
    float acc[32];
#pragma unroll
    for (int f = 0; f < 32; ++f)
        acc[f] = b2[f] + rx * W2[16*32+f] + ry * W2[17*32+f] + rz * W2[18*32+f];
    const float4* h4 = (const float4*)(h1 + (size_t)s * 16);
#pragma unroll
    for (int k4 = 0; k4 < 4; ++k4) {
        float4 h = h4[k4];
        float hv[4] = {h.x, h.y, h.z, h.w};
#pragma unroll
        for (int j = 0; j < 4; ++j) {
#pragma unroll
            for (int f = 0; f < 32; ++f)
                acc[f] += hv[j] * W2[(k4*4+j)*32 + f];
        }
    }
    unsigned* out = agg2 + (size_t)d * 32;
#pragma unroll
    for (int f = 0; f < 32; ++f) atomicMax(&out[f], enc(acc[f]));
}

// node2 + voxel pool: decode agg2, BN+ReLU, LDS max into 64x32 grid, flush.
__global__ __launch_bounds__(256) void node2_pool(
    const unsigned* __restrict__ agg2, const float* __restrict__ pos,
    const float* __restrict__ mean, const float* __restrict__ var,
    const float* __restrict__ gamma, const float* __restrict__ beta,
    unsigned* __restrict__ pool)   // [64*32] encoded
{
    __shared__ unsigned lpool[2048];
    for (int i = threadIdx.x; i < 2048; i += 256) lpool[i] = 0u;
    __syncthreads();
    const int per_block = N_NODES / 256;          // 1024 nodes per block
    const int iters = per_block * 32 / 256;       // 128
    int base_g = blockIdx.x * per_block * 32;
    for (int it = 0; it < iters; ++it) {
        int g = base_g + it * 256 + threadIdx.x;  // element id = n*32+f
        int n = g >> 5, f = g & 31;
        unsigned u = agg2[g];
        float v = (u == 0u) ? 0.0f : dec(u);
        float sc = gamma[f] * rsqrtf(var[f] + EPS_BN);
        float y = fmaxf((v - mean[f]) * sc + beta[f], 0.0f);
        int gx = (int)floorf(pos[3*n+0] * (1.0f/16.0f));
        int gy = (int)floorf(pos[3*n+1] * (1.0f/16.0f));
        int c = gx + gy * 8;
        c = min(max(c, 0), 63);
        atomicMax(&lpool[c*32 + f], enc(y));
    }
    __syncthreads();
    for (int i = threadIdx.x; i < 2048; i += 256) {
        unsigned u = lpool[i];
        if (u) atomicMax(&pool[i], u);
    }
}

// final: decode pooled grid to float output (sentinel -> 0).
__global__ __launch_bounds__(256) void pool_decode(
    const unsigned* __restrict__ pool, float* __restrict__ out)
{
    int i = blockIdx.x * 256 + threadIdx.x;   // 2048 threads
    unsigned u = pool[i];
    out[i] = (u == 0u) ? 0.0f : dec(u);
}

extern "C" void kernel_launch(void* const* d_in, const int* in_sizes, int n_in,
                              void* d_out, int out_size, void* d_ws, size_t ws_size,
                              hipStream_t stream) {
    const float* x    = (const float*)d_in[0];
    const float* pos  = (const float*)d_in[1];
    const int*   ei   = (const int*)d_in[2];
    const float* W1   = (const float*)d_in[3];
    const float* b1   = (const float*)d_in[4];
    const float* bn1m = (const float*)d_in[5];
    const float* bn1v = (const float*)d_in[6];
    const float* bn1w = (const float*)d_in[7];
    const float* bn1b = (const float*)d_in[8];
    const float* W2   = (const float*)d_in[9];
    const float* b2   = (const float*)d_in[10];
    const float* bn2m = (const float*)d_in[11];
    const float* bn2v = (const float*)d_in[12];
    const float* bn2w = (const float*)d_in[13];
    const float* bn2b = (const float*)d_in[14];

    unsigned* agg1 = (unsigned*)d_ws;                       // N*16 (also h1 in-place)
    unsigned* agg2 = agg1 + (size_t)N_NODES * 16;           // N*32
    unsigned* pool = agg2 + (size_t)N_NODES * 32;           // 2048

    size_t total_ws = ((size_t)N_NODES * 16 + (size_t)N_NODES * 32 + 2048) * 4;
    hipMemsetAsync(d_ws, 0, total_ws, stream);

    conv1_edges<<<N_EDGES/256, 256, 0, stream>>>(x, pos, ei, W1, b1, agg1);
    node1_bn<<<N_NODES*16/256, 256, 0, stream>>>(agg1, bn1m, bn1v, bn1w, bn1b);
    conv2_edges<<<N_EDGES/256, 256, 0, stream>>>((const float*)agg1, pos, ei, W2, b2, agg2);
    node2_pool<<<256, 256, 0, stream>>>(agg2, pos, bn2m, bn2v, bn2w, bn2b, pool);
    pool_decode<<<8, 256, 0, stream>>>(pool, (float*)d_out);
}

// Round 2
// 1482.531 us; speedup vs baseline: 2.8045x; 2.8045x over previous
//
#include <hip/hip_runtime.h>

#define N_NODES 262144
#define N_EDGES 2097152
#define EPS_BN 1e-5f

// Monotone float<->uint encoding: preserves order, 0 is a sentinel below everything.
__device__ __forceinline__ unsigned enc(float f) {
    unsigned u = __float_as_uint(f);
    return (u & 0x80000000u) ? ~u : (u | 0x80000000u);
}
__device__ __forceinline__ float dec(unsigned u) {
    unsigned b = (u & 0x80000000u) ? (u & 0x7FFFFFFFu) : ~u;
    return __uint_as_float(b);
}

// ---- CSR build ----

__global__ __launch_bounds__(256) void hist_k(const int* __restrict__ ei,
                                              int* __restrict__ deg) {
    int e = blockIdx.x * 256 + threadIdx.x;
    int d = ei[N_EDGES + e];
    atomicAdd(&deg[d], 1);
}

__global__ __launch_bounds__(256) void scan_block_sums(const int* __restrict__ deg,
                                                       int* __restrict__ bsum) {
    __shared__ int s[256];
    int t = threadIdx.x;
    s[t] = deg[blockIdx.x * 256 + t];
    __syncthreads();
    for (int off = 128; off > 0; off >>= 1) {
        if (t < off) s[t] += s[t + off];
        __syncthreads();
    }
    if (t == 0) bsum[blockIdx.x] = s[0];
}

__global__ __launch_bounds__(1024) void scan_top(const int* __restrict__ bsum,
                                                 int* __restrict__ boff) {
    __shared__ int s[1024];
    int t = threadIdx.x;
    int orig = bsum[t];
    s[t] = orig;
    __syncthreads();
    for (int off = 1; off < 1024; off <<= 1) {
        int v = (t >= off) ? s[t - off] : 0;
        __syncthreads();
        s[t] += v;
        __syncthreads();
    }
    boff[t] = s[t] - orig;   // exclusive
}

__global__ __launch_bounds__(256) void scan_final(const int* __restrict__ deg,
                                                  const int* __restrict__ boff,
                                                  int* __restrict__ offs,
                                                  int* __restrict__ cursor) {
    __shared__ int s[256];
    int t = threadIdx.x;
    int i = blockIdx.x * 256 + t;
    int v = deg[i];
    s[t] = v;
    __syncthreads();
    for (int off = 1; off < 256; off <<= 1) {
        int a = (t >= off) ? s[t - off] : 0;
        __syncthreads();
        s[t] += a;
        __syncthreads();
    }
    int ex = boff[blockIdx.x] + s[t] - v;
    offs[i] = ex;
    cursor[i] = ex;
}

__global__ __launch_bounds__(256) void scatter_k(const int* __restrict__ ei,
                                                 int* __restrict__ cursor,
                                                 int* __restrict__ csr_src) {
    int e = blockIdx.x * 256 + threadIdx.x;
    int s = ei[e];
    int d = ei[N_EDGES + e];
    int p = atomicAdd(&cursor[d], 1);
    csr_src[p] = s;
}

// ---- conv1: per-dst max over messages (1+3 -> 16), fused BN+ReLU ----
__global__ __launch_bounds__(256) void conv1_csr(
    const float* __restrict__ x, const float* __restrict__ pos,
    const int* __restrict__ offs, const int* __restrict__ cursor,
    const int* __restrict__ csr_src,
    const float* __restrict__ W1, const float* __restrict__ b1,
    const float* __restrict__ mean, const float* __restrict__ var,
    const float* __restrict__ gamma, const float* __restrict__ beta,
    float* __restrict__ h1)
{
    __shared__ float w[64], bs[16], scale[16], shift[16];
    if (threadIdx.x < 64) w[threadIdx.x] = W1[threadIdx.x];
    if (threadIdx.x < 16) {
        bs[threadIdx.x] = b1[threadIdx.x];
        float sc = gamma[threadIdx.x] * rsqrtf(var[threadIdx.x] + EPS_BN);
        scale[threadIdx.x] = sc;
        shift[threadIdx.x] = beta[threadIdx.x] - mean[threadIdx.x] * sc;
    }
    __syncthreads();
    int d = blockIdx.x * 256 + threadIdx.x;
    int start = offs[d], end = cursor[d];
    float px = pos[3*d], py = pos[3*d+1], pz = pos[3*d+2];
    float acc[16];
#pragma unroll
    for (int f = 0; f < 16; ++f) acc[f] = -INFINITY;
    for (int j = start; j < end; ++j) {
        int s = csr_src[j];
        float xs = x[s];
        float rx = pos[3*s] - px, ry = pos[3*s+1] - py, rz = pos[3*s+2] - pz;
#pragma unroll
        for (int f = 0; f < 16; ++f) {
            float m = bs[f] + xs*w[f] + rx*w[16+f] + ry*w[32+f] + rz*w[48+f];
            acc[f] = fmaxf(acc[f], m);
        }
    }
    bool any = end > start;
#pragma unroll
    for (int f = 0; f < 16; ++f) {
        float v = any ? acc[f] : 0.0f;
        h1[(size_t)d*16 + f] = fmaxf(v * scale[f] + shift[f], 0.0f);
    }
}

// ---- conv2 + voxel pool fused: per-dst max (16+3 -> 32), BN+ReLU, LDS pool ----
__global__ __launch_bounds__(256) void conv2_csr_pool(
    const float* __restrict__ h1, const float* __restrict__ pos,
    const int* __restrict__ offs, const int* __restrict__ cursor,
    const int* __restrict__ csr_src,
    const float* __restrict__ W2, const float* __restrict__ b2,
    const float* __restrict__ mean, const float* __restrict__ var,
    const float* __restrict__ gamma, const float* __restrict__ beta,
    unsigned* __restrict__ pool)
{
    __shared__ float w[608], bs[32], scale[32], shift[32];
    __shared__ unsigned lpool[2048];
    for (int i = threadIdx.x; i < 608; i += 256) w[i] = W2[i];
    if (threadIdx.x < 32) {
        bs[threadIdx.x] = b2[threadIdx.x];
        float sc = gamma[threadIdx.x] * rsqrtf(var[threadIdx.x] + EPS_BN);
        scale[threadIdx.x] = sc;
        shift[threadIdx.x] = beta[threadIdx.x] - mean[threadIdx.x] * sc;
    }
    for (int i = threadIdx.x; i < 2048; i += 256) lpool[i] = 0u;
    __syncthreads();

    int d = blockIdx.x * 256 + threadIdx.x;
    int start = offs[d], end = cursor[d];
    float px = pos[3*d], py = pos[3*d+1], pz = pos[3*d+2];
    float acc[32];
#pragma unroll
    for (int f = 0; f < 32; ++f) acc[f] = -INFINITY;
    for (int j = start; j < end; ++j) {
        int s = csr_src[j];
        const float4* h4 = (const float4*)(h1 + (size_t)s * 16);
        float4 a0 = h4[0], a1 = h4[1], a2 = h4[2], a3 = h4[3];
        float rx = pos[3*s] - px, ry = pos[3*s+1] - py, rz = pos[3*s+2] - pz;
        float hv[16] = {a0.x,a0.y,a0.z,a0.w, a1.x,a1.y,a1.z,a1.w,
                        a2.x,a2.y,a2.z,a2.w, a3.x,a3.y,a3.z,a3.w};
        float msg[32];
#pragma unroll
        for (int f = 0; f < 32; ++f)
            msg[f] = bs[f] + rx*w[16*32+f] + ry*w[17*32+f] + rz*w[18*32+f];
#pragma unroll
        for (int k = 0; k < 16; ++k)
#pragma unroll
            for (int f = 0; f < 32; ++f)
                msg[f] += hv[k] * w[k*32 + f];
#pragma unroll
        for (int f = 0; f < 32; ++f) acc[f] = fmaxf(acc[f], msg[f]);
    }
    bool any = end > start;
    int gx = (int)floorf(px * (1.0f/16.0f));
    int gy = (int)floorf(py * (1.0f/16.0f));
    int c = min(max(gx + gy*8, 0), 63);
#pragma unroll
    for (int f = 0; f < 32; ++f) {
        float v = any ? acc[f] : 0.0f;
        float y = fmaxf(v * scale[f] + shift[f], 0.0f);
        atomicMax(&lpool[c*32 + f], enc(y));
    }
    __syncthreads();
    for (int i = threadIdx.x; i < 2048; i += 256) {
        unsigned u = lpool[i];
        if (u) atomicMax(&pool[i], u);
    }
}

__global__ __launch_bounds__(256) void pool_decode(const unsigned* __restrict__ pool,
                                                   float* __restrict__ out) {
    int i = blockIdx.x * 256 + threadIdx.x;   // 2048
    unsigned u = pool[i];
    out[i] = (u == 0u) ? 0.0f : dec(u);
}

extern "C" void kernel_launch(void* const* d_in, const int* in_sizes, int n_in,
                              void* d_out, int out_size, void* d_ws, size_t ws_size,
                              hipStream_t stream) {
    const float* x    = (const float*)d_in[0];
    const float* pos  = (const float*)d_in[1];
    const int*   ei   = (const int*)d_in[2];
    const float* W1   = (const float*)d_in[3];
    const float* b1   = (const float*)d_in[4];
    const float* bn1m = (const float*)d_in[5];
    const float* bn1v = (const float*)d_in[6];
    const float* bn1w = (const float*)d_in[7];
    const float* bn1b = (const float*)d_in[8];
    const float* W2   = (const float*)d_in[9];
    const float* b2   = (const float*)d_in[10];
    const float* bn2m = (const float*)d_in[11];
    const float* bn2v = (const float*)d_in[12];
    const float* bn2w = (const float*)d_in[13];
    const float* bn2b = (const float*)d_in[14];

    int* deg      = (int*)d_ws;                    // N (zeroed)
    unsigned* pool = (unsigned*)(deg + N_NODES);   // 2048 (zeroed)
    int* offs     = (int*)(pool + 2048);           // N
    int* cursor   = offs + N_NODES;                // N
    int* csr_src  = cursor + N_NODES;              // E
    float* h1     = (float*)(csr_src + N_EDGES);   // N*16
    int* bsum     = (int*)(h1 + (size_t)N_NODES*16); // 1024
    int* boff     = bsum + 1024;                   // 1024

    hipMemsetAsync(d_ws, 0, (size_t)(N_NODES + 2048) * 4, stream);

    hist_k        <<<N_EDGES/256, 256, 0, stream>>>(ei, deg);
    scan_block_sums<<<N_NODES/256, 256, 0, stream>>>(deg, bsum);
    scan_top      <<<1, 1024, 0, stream>>>(bsum, boff);
    scan_final    <<<N_NODES/256, 256, 0, stream>>>(deg, boff, offs, cursor);
    scatter_k     <<<N_EDGES/256, 256, 0, stream>>>(ei, cursor, csr_src);
    conv1_csr     <<<N_NODES/256, 256, 0, stream>>>(x, pos, offs, cursor, csr_src,
                                                    W1, b1, bn1m, bn1v, bn1w, bn1b, h1);
    conv2_csr_pool<<<N_NODES/256, 256, 0, stream>>>(h1, pos, offs, cursor, csr_src,
                                                    W2, b2, bn2m, bn2v, bn2w, bn2b, pool);
    pool_decode   <<<8, 256, 0, stream>>>(pool, (float*)d_out);
}